// Round 1
// baseline (902.754 us; speedup 1.0000x reference)
//
#include <hip/hip_runtime.h>

#define NTGT 2048
#define NSRC 4096
#define NPATCH 32
#define CT 512
#define NY 48
#define NCG 3436
#define NTERMS 34
#define NITEMS (NTERMS*24)

// term tables: order matches reference out[J] concatenation order
__constant__ int T_j[NTERMS]    = {0,1,2,3, 1,0,1,2,1,2,3,2,3, 2,0,1,2,3,1,2,3,1,2,3, 3,0,2,3,1,2,3,1,2,3};
__constant__ int T_l[NTERMS]    = {0,1,2,3, 0,1,1,1,2,2,2,3,3, 0,2,1,1,1,2,2,2,3,3,3, 0,3,1,1,2,2,2,3,3,3};
__constant__ int T_Jv[NTERMS]   = {0,0,0,0, 1,1,1,1,1,1,1,1,1, 2,2,2,2,2,2,2,2,2,2,2, 3,3,3,3,3,3,3,3,3,3};
__constant__ int T_cgoff[NTERMS]= {0,1,10,35, 84,93,102,129,174,219,294,399,504,
                                   651,676,701,746,821,926,1001,1126,1301,1406,1581,
                                   1826,1875,1924,2029,2176,2281,2456,2701,2848,3093};
__constant__ int T_col[NTERMS]  = {0,1,2,3, 0,1,2,3,4,5,6,7,8, 0,1,2,3,4,5,6,7,8,9,10, 0,1,2,3,4,5,6,7,8,9};
__constant__ int OUT_BASE[4] = {0, 1572864, 12189696, 33816576};
__constant__ int OUT_W[4]    = {384, 864, 1056, 960};

// ---------------- CG table construction (device, double precision) ----------------
__device__ double factd(int n) { double r = 1.0; for (int i = 2; i <= n; ++i) r *= i; return r; }

__device__ double su2_cg(int j1, int m1, int j2, int m2, int j3, int m3) {
  if (m3 != m1 + m2) return 0.0;
  int vmin = max(max(-j1 + j2 + m3, -j1 + m1), 0);
  int vmax = min(min(j2 + j3 + m1, j3 - j1 + j2), j3 + m3);
  double cc = sqrt((2.0*j3 + 1.0) * factd(j3 + j1 - j2) * factd(j3 - j1 + j2) * factd(j1 + j2 - j3)
                   / factd(j1 + j2 + j3 + 1)
                   * factd(j3 + m3) * factd(j3 - m3)
                   / (factd(j1 - m1) * factd(j1 + m1) * factd(j2 - m2) * factd(j2 + m2)));
  double s = 0.0;
  for (int v = vmin; v <= vmax; ++v) {
    double sgn = ((v + j2 + m2) & 1) ? -1.0 : 1.0;
    s += sgn * factd(j2 + j3 + m1 - v) * factd(j1 - m1 + v)
         / (factd(v) * factd(j3 - j1 + j2 - v) * factd(j3 + m3 - v) * factd(v + j1 - j2 - m3));
  }
  return cc * s;
}

struct C2 { double re, im; };

__device__ C2 qent(int l, int r, int c) {
  // real->complex change-of-basis matrix entry q[r][c], including (-i)^l phase
  double re = 0.0, im = 0.0;
  const double is2 = 0.70710678118654752440;
  int m = r - l;
  if (m < 0) {
    if (c == l - m) re = is2;           // l + |m|
    else if (c == l + m) im = -is2;     // l - |m|
  } else if (m == 0) {
    if (c == l) re = 1.0;
  } else {
    double sgn = (m & 1) ? -1.0 : 1.0;
    if (c == l + m) re = sgn * is2;
    else if (c == l - m) im = sgn * is2;
  }
  // multiply by (-i)^l : l=0 ->1, 1 -> -i, 2 -> -1, 3 -> i
  const double pr[4] = {1.0, 0.0, -1.0, 0.0};
  const double pi[4] = {0.0, -1.0, 0.0, 1.0};
  double a = pr[l & 3], bb = pi[l & 3];
  C2 o; o.re = re * a - im * bb; o.im = re * bb + im * a; return o;
}

__device__ float real_cg(int j, int l, int J, int a, int b, int c) {
  double acc = 0.0;
  for (int i = 0; i < 2*j + 1; ++i) {
    for (int k = 0; k < 2*l + 1; ++k) {
      int m = (i - j) + (k - l) + J;
      if (m < 0 || m > 2*J) continue;
      double cg = su2_cg(j, i - j, l, k - l, J, m - J);
      if (cg == 0.0) continue;
      C2 qa = qent(j, i, a), qb = qent(l, k, b), qc = qent(J, m, c);
      double r1 = qa.re * qb.re - qa.im * qb.im;
      double i1 = qa.re * qb.im + qa.im * qb.re;
      // times conj(qc)
      double rr = r1 * qc.re + i1 * qc.im;
      acc += rr * cg;
    }
  }
  return (float)acc;
}

__global__ void cg_init_kernel(float* __restrict__ cg) {
  int t = blockIdx.x;
  int j = T_j[t], l = T_l[t], J = T_Jv[t], off = T_cgoff[t];
  int nj = 2*j + 1, nl = 2*l + 1, nJ = 2*J + 1;
  int n = nj * nl * nJ;
  for (int i = threadIdx.x; i < n; i += blockDim.x) {
    int a = i / (nl * nJ);
    int r = i - a * nl * nJ;
    int bb = r / nJ;
    int cc = r - bb * nJ;
    float v;
    if (l == 0 && j == 0)      v = 1.0f;
    else if (l == 0)           v = (a == cc) ? 1.0f : 0.0f;   // A-terms: delta(m_j, m_J)
    else if (j == 0)           v = (bb == cc) ? 1.0f : 0.0f;  // B-terms: delta(m_l, m_J)
    else                       v = real_cg(j, l, J, a, bb, cc);
    cg[off + i] = v;
  }
}

// ---------------- main fused kernel ----------------
template<int NJ>
__device__ __forceinline__ void do_term(const float* y_lds, const float* cg_lds,
                                        float* __restrict__ out,
                                        int j, int l, int cgo, long obase,
                                        int s, int ch4, int W) {
  const int nj = 2*j + 1, nl = 2*l + 1;
  const int offj = j * j;
  const int colbase = l * l * 32 + ch4 * 4;
  float acc[NJ][4];
  #pragma unroll
  for (int z = 0; z < NJ; ++z) { acc[z][0] = 0.f; acc[z][1] = 0.f; acc[z][2] = 0.f; acc[z][3] = 0.f; }
  for (int ml = 0; ml < nl; ++ml) {
    for (int mj = 0; mj < nj; ++mj) {
      const float4 yq = *(const float4*)&y_lds[((offj + mj) * 3 + s) * CT + colbase + ml * 32];
      const float* cgp = &cg_lds[cgo + (mj * nl + ml) * NJ];
      #pragma unroll
      for (int z = 0; z < NJ; ++z) {
        const float cc = cgp[z];
        acc[z][0] = fmaf(cc, yq.x, acc[z][0]);
        acc[z][1] = fmaf(cc, yq.y, acc[z][1]);
        acc[z][2] = fmaf(cc, yq.z, acc[z][2]);
        acc[z][3] = fmaf(cc, yq.w, acc[z][3]);
      }
    }
  }
  #pragma unroll
  for (int z = 0; z < NJ; ++z) {
    float4 o; o.x = acc[z][0]; o.y = acc[z][1]; o.z = acc[z][2]; o.w = acc[z][3];
    *(float4*)&out[obase + (long)z * W] = o;
  }
}

__global__ __launch_bounds__(512) void sh_conv_kernel(
    const float* __restrict__ f0, const float* __restrict__ f1,
    const float* __restrict__ f2, const float* __restrict__ f3,
    const float* __restrict__ kern, const int* __restrict__ pidx,
    const float* __restrict__ cg, float* __restrict__ out) {
  __shared__ float y_lds[NY * CT];   // 96 KB
  __shared__ float cg_lds[NCG];      // 13.7 KB
  const int tid = threadIdx.x;
  const int bv = blockIdx.x;
  const int b = bv >> 11;

  for (int i = tid; i < NCG; i += 512) cg_lds[i] = cg[i];

  // ---- phase 1: y = K^T @ gathered patch columns; thread owns column c = tid
  const int c = tid;
  const float* src; int w;
  if (c < 32)       { src = f0 + (size_t)b * NSRC * 32  + c;         w = 32;  }
  else if (c < 128) { src = f1 + (size_t)b * NSRC * 96  + (c - 32);  w = 96;  }
  else if (c < 288) { src = f2 + (size_t)b * NSRC * 160 + (c - 128); w = 160; }
  else              { src = f3 + (size_t)b * NSRC * 224 + (c - 288); w = 224; }

  const int* ip = pidx + (size_t)bv * NPATCH;   // uniform -> scalar loads
  float vals[NPATCH];
  #pragma unroll
  for (int p = 0; p < NPATCH; ++p) vals[p] = src[(size_t)ip[p] * w];

  float acc[NY];
  #pragma unroll
  for (int y = 0; y < NY; ++y) acc[y] = 0.f;

  const float* kb = kern + (size_t)bv * NPATCH * NY;  // uniform -> scalar loads
  #pragma unroll
  for (int p = 0; p < NPATCH; ++p) {
    const float vp = vals[p];
    #pragma unroll
    for (int y = 0; y < NY; ++y) acc[y] = fmaf(kb[p * NY + y], vp, acc[y]);
  }
  #pragma unroll
  for (int y = 0; y < NY; ++y) y_lds[y * CT + c] = acc[y];

  __syncthreads();

  // ---- phase 2: CG contraction; item = (term, s, ch4)
  for (int it = tid; it < NITEMS; it += 512) {
    const int term = it / 24;
    const int rem  = it - term * 24;
    const int s = rem >> 3, ch4 = rem & 7;
    const int j = T_j[term], l = T_l[term], J = T_Jv[term];
    const int cgo = T_cgoff[term];
    const int W = OUT_W[J];
    const long obase = (long)OUT_BASE[J] + ((long)bv * (2*J + 1)) * W
                     + T_col[term] * 96 + s * 32 + ch4 * 4;
    switch (J) {
      case 0:  do_term<1>(y_lds, cg_lds, out, j, l, cgo, obase, s, ch4, W); break;
      case 1:  do_term<3>(y_lds, cg_lds, out, j, l, cgo, obase, s, ch4, W); break;
      case 2:  do_term<5>(y_lds, cg_lds, out, j, l, cgo, obase, s, ch4, W); break;
      default: do_term<7>(y_lds, cg_lds, out, j, l, cgo, obase, s, ch4, W); break;
    }
  }
}

extern "C" void kernel_launch(void* const* d_in, const int* in_sizes, int n_in,
                              void* d_out, int out_size, void* d_ws, size_t ws_size,
                              hipStream_t stream) {
  const float* f0   = (const float*)d_in[0];
  const float* f1   = (const float*)d_in[1];
  const float* f2   = (const float*)d_in[2];
  const float* f3   = (const float*)d_in[3];
  const float* kern = (const float*)d_in[4];
  const int*   pidx = (const int*)d_in[5];
  float* out = (float*)d_out;
  float* cg  = (float*)d_ws;

  hipLaunchKernelGGL(cg_init_kernel, dim3(NTERMS), dim3(64), 0, stream, cg);
  hipLaunchKernelGGL(sh_conv_kernel, dim3(2 * NTGT), dim3(512), 0, stream,
                     f0, f1, f2, f3, kern, pidx, cg, out);
}

// Round 2
// 486.686 us; speedup vs baseline: 1.8549x; 1.8549x over previous
//
#include <hip/hip_runtime.h>

#define NTGT 2048
#define NSRC 4096
#define NPATCH 32
#define NY 48
#define NCG 3436
#define NTERMS 34
#define NCOL 128
#define PITCH 132

// term tables: order matches reference out[J] concatenation order
__constant__ int T_j[NTERMS]    = {0,1,2,3, 1,0,1,2,1,2,3,2,3, 2,0,1,2,3,1,2,3,1,2,3, 3,0,2,3,1,2,3,1,2,3};
__constant__ int T_l[NTERMS]    = {0,1,2,3, 0,1,1,1,2,2,2,3,3, 0,2,1,1,1,2,2,2,3,3,3, 0,3,1,1,2,2,2,3,3,3};
__constant__ int T_Jv[NTERMS]   = {0,0,0,0, 1,1,1,1,1,1,1,1,1, 2,2,2,2,2,2,2,2,2,2,2, 3,3,3,3,3,3,3,3,3,3};
__constant__ int T_cgoff[NTERMS]= {0,1,10,35, 84,93,102,129,174,219,294,399,504,
                                   651,676,701,746,821,926,1001,1126,1301,1406,1581,
                                   1826,1875,1924,2029,2176,2281,2456,2701,2848,3093};
__constant__ int T_col[NTERMS]  = {0,1,2,3, 0,1,2,3,4,5,6,7,8, 0,1,2,3,4,5,6,7,8,9,10, 0,1,2,3,4,5,6,7,8,9};
__constant__ int OUT_BASE[4] = {0, 1572864, 12189696, 33816576};
__constant__ int OUT_W[4]    = {384, 864, 1056, 960};

// ---------------- CG table construction (device, double precision) ----------------
__device__ double factd(int n) { double r = 1.0; for (int i = 2; i <= n; ++i) r *= i; return r; }

__device__ double su2_cg(int j1, int m1, int j2, int m2, int j3, int m3) {
  if (m3 != m1 + m2) return 0.0;
  int vmin = max(max(-j1 + j2 + m3, -j1 + m1), 0);
  int vmax = min(min(j2 + j3 + m1, j3 - j1 + j2), j3 + m3);
  double cc = sqrt((2.0*j3 + 1.0) * factd(j3 + j1 - j2) * factd(j3 - j1 + j2) * factd(j1 + j2 - j3)
                   / factd(j1 + j2 + j3 + 1)
                   * factd(j3 + m3) * factd(j3 - m3)
                   / (factd(j1 - m1) * factd(j1 + m1) * factd(j2 - m2) * factd(j2 + m2)));
  double s = 0.0;
  for (int v = vmin; v <= vmax; ++v) {
    double sgn = ((v + j2 + m2) & 1) ? -1.0 : 1.0;
    s += sgn * factd(j2 + j3 + m1 - v) * factd(j1 - m1 + v)
         / (factd(v) * factd(j3 - j1 + j2 - v) * factd(j3 + m3 - v) * factd(v + j1 - j2 - m3));
  }
  return cc * s;
}

struct C2 { double re, im; };

__device__ C2 qent(int l, int r, int c) {
  double re = 0.0, im = 0.0;
  const double is2 = 0.70710678118654752440;
  int m = r - l;
  if (m < 0) {
    if (c == l - m) re = is2;
    else if (c == l + m) im = -is2;
  } else if (m == 0) {
    if (c == l) re = 1.0;
  } else {
    double sgn = (m & 1) ? -1.0 : 1.0;
    if (c == l + m) re = sgn * is2;
    else if (c == l - m) im = sgn * is2;
  }
  const double pr[4] = {1.0, 0.0, -1.0, 0.0};
  const double pi[4] = {0.0, -1.0, 0.0, 1.0};
  double a = pr[l & 3], bb = pi[l & 3];
  C2 o; o.re = re * a - im * bb; o.im = re * bb + im * a; return o;
}

// One block per term; su2 values depend only on (i,k) -> shared table (the
// round-1 version recomputed su2_cg per (a,b,c) entry: 168k calls, ~316us).
__global__ void cg_init_kernel(float* __restrict__ cg) {
  __shared__ double su2_tab[49];
  const int t = blockIdx.x;
  const int j = T_j[t], l = T_l[t], J = T_Jv[t], off = T_cgoff[t];
  const int nj = 2*j + 1, nl = 2*l + 1, nJ = 2*J + 1;
  const bool triv = (l == 0 || j == 0);
  if (!triv) {
    for (int ik = threadIdx.x; ik < nj * nl; ik += blockDim.x) {
      int i = ik / nl, k = ik - (ik / nl) * nl;
      int m = (i - j) + (k - l) + J;
      su2_tab[ik] = (m >= 0 && m <= 2*J) ? su2_cg(j, i - j, l, k - l, J, m - J) : 0.0;
    }
  }
  __syncthreads();
  const int n = nj * nl * nJ;
  for (int e = threadIdx.x; e < n; e += blockDim.x) {
    int a = e / (nl * nJ);
    int r = e - a * nl * nJ;
    int bb = r / nJ;
    int cc = r - bb * nJ;
    float v;
    if (j == 0 && l == 0)      v = 1.0f;
    else if (l == 0)           v = (a == cc) ? 1.0f : 0.0f;
    else if (j == 0)           v = (bb == cc) ? 1.0f : 0.0f;
    else {
      double acc = 0.0;
      for (int i = 0; i < nj; ++i) {
        for (int k = 0; k < nl; ++k) {
          int m = (i - j) + (k - l) + J;
          if (m < 0 || m > 2*J) continue;
          double s2 = su2_tab[i * nl + k];
          if (s2 == 0.0) continue;
          C2 qa = qent(j, i, a), qb = qent(l, k, bb), qc = qent(J, m, cc);
          double r1 = qa.re * qb.re - qa.im * qb.im;
          double i1 = qa.re * qb.im + qa.im * qb.re;
          acc += (r1 * qc.re + i1 * qc.im) * s2;
        }
      }
      v = (float)acc;
    }
    cg[off + e] = v;
  }
}

// ---------------- main fused kernel ----------------
template<int NJ>
__device__ __forceinline__ void do_term(const float* y_lds, const float* cg_lds,
                                        float* __restrict__ out,
                                        int j, int l, int cgo, size_t obase,
                                        int s, int ch4, int W) {
  const int nj = 2*j + 1, nl = 2*l + 1;
  const int rowbase = j*j*3 + s;          // row = (j*j + mj)*3 + s
  const int colbase = l*l*8 + ch4*4;
  float acc[NJ][4];
  #pragma unroll
  for (int z = 0; z < NJ; ++z) { acc[z][0]=0.f; acc[z][1]=0.f; acc[z][2]=0.f; acc[z][3]=0.f; }
  for (int ml = 0; ml < nl; ++ml) {
    for (int mj = 0; mj < nj; ++mj) {
      const float4 yq = *(const float4*)&y_lds[(rowbase + mj*3) * PITCH + colbase + ml*8];
      const float* cgp = &cg_lds[cgo + (mj * nl + ml) * NJ];
      #pragma unroll
      for (int z = 0; z < NJ; ++z) {
        const float cc = cgp[z];
        acc[z][0] = fmaf(cc, yq.x, acc[z][0]);
        acc[z][1] = fmaf(cc, yq.y, acc[z][1]);
        acc[z][2] = fmaf(cc, yq.z, acc[z][2]);
        acc[z][3] = fmaf(cc, yq.w, acc[z][3]);
      }
    }
  }
  #pragma unroll
  for (int z = 0; z < NJ; ++z) {
    float4 o; o.x = acc[z][0]; o.y = acc[z][1]; o.z = acc[z][2]; o.w = acc[z][3];
    *(float4*)&out[obase + (size_t)z * W] = o;
  }
}

__global__ __launch_bounds__(512, 6) void sh_conv_kernel(
    const float* __restrict__ f0, const float* __restrict__ f1,
    const float* __restrict__ f2, const float* __restrict__ f3,
    const float* __restrict__ kern, const int* __restrict__ pidx,
    const float* __restrict__ cg, float* __restrict__ out) {
  __shared__ float y_lds[NY * PITCH];   // 48*132*4 = 25.3 KB (padded: no bank conflicts)
  __shared__ float cg_lds[NCG];         // 13.7 KB
  const int tid = threadIdx.x;
  // XCD-cohort swizzle: the 4 channel-blocks of one bv land on the same XCD
  const int xcd  = blockIdx.x & 7;
  const int slot = blockIdx.x >> 3;
  const int bv   = ((slot >> 2) << 3) | xcd;   // 0..4095
  const int cb   = slot & 3;                   // channel group: ch in [cb*8, cb*8+8)
  const int b    = bv >> 11;

  for (int i = tid; i < NCG; i += 512) cg_lds[i] = cg[i];

  // ---- phase 1: y = K^T @ gathered patch columns
  // 128 columns (8 channels x 16 sh-rows), 4 row-groups of 12 y-rows each
  const int col = tid & (NCOL - 1);
  const int rg  = tid >> 7;           // uniform per wave
  const float* fptr; int w, r;
  if (col < 8)       { fptr = f0; w = 32;  r = col; }
  else if (col < 32) { fptr = f1; w = 96;  r = col - 8; }
  else if (col < 72) { fptr = f2; w = 160; r = col - 32; }
  else               { fptr = f3; w = 224; r = col - 72; }
  const int ml = r >> 3, chl = r & 7;
  const float* src = fptr + (size_t)b * NSRC * w + ml * 32 + cb * 8 + chl;
  const int* ip = pidx + (size_t)bv * NPATCH;                 // uniform -> s_load
  const float* kb = kern + (size_t)bv * NPATCH * NY + rg * 12; // uniform -> s_load

  float acc[12];
  #pragma unroll
  for (int y = 0; y < 12; ++y) acc[y] = 0.f;
  #pragma unroll
  for (int pc = 0; pc < 4; ++pc) {
    float vals[8];
    #pragma unroll
    for (int p = 0; p < 8; ++p) vals[p] = src[(size_t)ip[pc * 8 + p] * w];
    #pragma unroll
    for (int p = 0; p < 8; ++p) {
      const float* kp = kb + (pc * 8 + p) * NY;
      const float vp = vals[p];
      #pragma unroll
      for (int y = 0; y < 12; ++y) acc[y] = fmaf(kp[y], vp, acc[y]);
    }
  }
  #pragma unroll
  for (int y = 0; y < 12; ++y) y_lds[(rg * 12 + y) * PITCH + col] = acc[y];

  __syncthreads();

  // ---- phase 2: CG contraction; item = (term, s, ch4), 204 items, single pass
  if (tid < NTERMS * 6) {
    const int term = tid / 6;
    const int rem  = tid - term * 6;
    const int s = rem >> 1, ch4 = rem & 1;
    const int j = T_j[term], l = T_l[term], J = T_Jv[term];
    const int cgo = T_cgoff[term];
    const int W = OUT_W[J];
    const size_t obase = (size_t)OUT_BASE[J] + (size_t)bv * (2*J + 1) * W
                       + T_col[term] * 96 + s * 32 + cb * 8 + ch4 * 4;
    switch (J) {
      case 0:  do_term<1>(y_lds, cg_lds, out, j, l, cgo, obase, s, ch4, W); break;
      case 1:  do_term<3>(y_lds, cg_lds, out, j, l, cgo, obase, s, ch4, W); break;
      case 2:  do_term<5>(y_lds, cg_lds, out, j, l, cgo, obase, s, ch4, W); break;
      default: do_term<7>(y_lds, cg_lds, out, j, l, cgo, obase, s, ch4, W); break;
    }
  }
}

extern "C" void kernel_launch(void* const* d_in, const int* in_sizes, int n_in,
                              void* d_out, int out_size, void* d_ws, size_t ws_size,
                              hipStream_t stream) {
  const float* f0   = (const float*)d_in[0];
  const float* f1   = (const float*)d_in[1];
  const float* f2   = (const float*)d_in[2];
  const float* f3   = (const float*)d_in[3];
  const float* kern = (const float*)d_in[4];
  const int*   pidx = (const int*)d_in[5];
  float* out = (float*)d_out;
  float* cg  = (float*)d_ws;

  hipLaunchKernelGGL(cg_init_kernel, dim3(NTERMS), dim3(256), 0, stream, cg);
  hipLaunchKernelGGL(sh_conv_kernel, dim3(4 * 2 * NTGT), dim3(512), 0, stream,
                     f0, f1, f2, f3, kern, pidx, cg, out);
}